// Round 3
// baseline (580.789 us; speedup 1.0000x reference)
//
#include <hip/hip_runtime.h>
#include <hip/hip_bf16.h>

#define DIM 512
#define BM 32

typedef __bf16 bf16x8 __attribute__((ext_vector_type(8)));
typedef float f32x16 __attribute__((ext_vector_type(16)));
typedef float f32x4  __attribute__((ext_vector_type(4)));   // clang vector: OK for nontemporal builtins

union B128 { uint4 u; bf16x8 v; };
union PK  { ushort4 h[2]; uint4 u; };
union F4  { float4 hip; f32x4 cv; };

__device__ __forceinline__ unsigned short f2bf(float f) {
    union { __hip_bfloat16 b; unsigned short u; } c;
    c.b = __float2bfloat16(f);
    return c.u;
}

__device__ __forceinline__ void nt_store4(const float4& v, float* p) {
    F4 u; u.hip = v;
    __builtin_nontemporal_store(u.cv, (f32x4*)p);
}

// S_frag: B-fragment-linear layout of S = A + A^T (bf16).
// chunk c = (nt2*32 + ks)*64 + l   (16 B = 8 bf16 each):
//   content = S[e][d0 .. d0+7],  e = nt2*32 + (l&31),  d0 = ks*16 + (l>>5)*8
// => a wave's B-fragment load for (nt2, ks) is 64 consecutive 16B chunks
//    (one fully-coalesced global_load_dwordx4, L2-resident).
__global__ void prep_s_kernel(const float* __restrict__ A,
                              unsigned short* __restrict__ Sf) {
    const int c   = blockIdx.x * 256 + threadIdx.x;   // 0..32767
    const int l   = c & 63;
    const int ks  = (c >> 6) & 31;
    const int nt2 = c >> 11;
    const int e   = nt2 * 32 + (l & 31);
    const int d0  = ks * 16 + (l >> 5) * 8;
    float4 r0 = *(const float4*)(A + (size_t)e * DIM + d0);
    float4 r1 = *(const float4*)(A + (size_t)e * DIM + d0 + 4);
    float cl[8];
    #pragma unroll
    for (int j = 0; j < 8; ++j) cl[j] = A[(size_t)(d0 + j) * DIM + e];
    ushort4 o0, o1;
    o0.x = f2bf(r0.x + cl[0]); o0.y = f2bf(r0.y + cl[1]);
    o0.z = f2bf(r0.z + cl[2]); o0.w = f2bf(r0.w + cl[3]);
    o1.x = f2bf(r1.x + cl[4]); o1.y = f2bf(r1.y + cl[5]);
    o1.z = f2bf(r1.z + cl[6]); o1.w = f2bf(r1.w + cl[7]);
    *(ushort4*)(Sf + (size_t)c * 8)     = o0;
    *(ushort4*)(Sf + (size_t)c * 8 + 4) = o1;
}

// out[b][0:512]   = p[b] + q[b] . S^T   (S symmetric)
// out[b][512:1024]= q[b]                 (exact fp32 copy, fused into staging)
//
// BM=32, 256 threads (4 waves), 32 KB LDS -> 4 blocks/CU: 4 independent
// HBM streams per CU so other blocks' streaming covers each block's
// barrier/K-loop gaps. Staging is 16B-chunk-per-lane (ds_write_b128,
// XOR-swizzled: all 32 banks, <=2-way). K loop barrier-free, B frags
// straight from L2. Epilogue: p-loads hoisted over the LDS transpose,
// nontemporal stores.
__global__ __launch_bounds__(256, 4) void fused_gemm_kernel(
        const float* __restrict__ pq,
        const unsigned short* __restrict__ Sf,
        float* __restrict__ out) {
    __shared__ __align__(16) unsigned char smem[32768];
    unsigned short* As = (unsigned short*)smem;   // 32x512 bf16, frag-linear
    float*          Cs = (float*)smem;            // epilogue: 32x256 f32

    const int t = threadIdx.x;
    const int l = t & 63;
    const int w = t >> 6;          // wave 0..3 == N position
    const int lane31 = l & 31;
    const int half   = l >> 5;
    const int m0 = blockIdx.x * BM;

    // ---- stage q: 32x512 fp32. Each thread-iter: one 16B bf16 chunk.
    // chunk (ks, lpos): lpos = row + 32*hi, holds q[row][ks*16+hi*8 ..+7],
    // stored at chunk index ks*64 + (lpos ^ (ks&7)).
    // Write banks: addr = ks*1024 + f*16; f&7 = (row&7)^(ks&7) spans all 8
    // octets across a wave's 32 ks values -> 32 banks, 2-way (free).
    float4 qv[16];
    #pragma unroll
    for (int p = 0; p < 8; ++p) {
        const int c    = p * 256 + t;        // 0..2047
        const int row  = c >> 6;             // 0..31  (one row per wave-iter)
        const int col0 = (c & 63) * 8;       // 0,8,..,504
        const size_t goff = (size_t)(m0 + row) * (2 * DIM) + DIM + col0;
        qv[2 * p]     = *(const float4*)(pq + goff);
        qv[2 * p + 1] = *(const float4*)(pq + goff + 4);
    }
    #pragma unroll
    for (int p = 0; p < 8; ++p) {
        const int c    = p * 256 + t;
        const int row  = c >> 6;
        const int w6   = c & 63;
        const int ks   = w6 >> 1;
        const int hi   = w6 & 1;
        const int col0 = w6 * 8;
        const size_t goff = (size_t)(m0 + row) * (2 * DIM) + DIM + col0;
        nt_store4(qv[2 * p],     out + goff);
        nt_store4(qv[2 * p + 1], out + goff + 4);
        PK pk;
        pk.h[0].x = f2bf(qv[2 * p].x);     pk.h[0].y = f2bf(qv[2 * p].y);
        pk.h[0].z = f2bf(qv[2 * p].z);     pk.h[0].w = f2bf(qv[2 * p].w);
        pk.h[1].x = f2bf(qv[2 * p + 1].x); pk.h[1].y = f2bf(qv[2 * p + 1].y);
        pk.h[1].z = f2bf(qv[2 * p + 1].z); pk.h[1].w = f2bf(qv[2 * p + 1].w);
        const int f = (row + 32 * hi) ^ (ks & 7);
        *(uint4*)(As + (size_t)(ks * 64 + f) * 8) = pk.u;
    }
    __syncthreads();

    f32x16 acc[4];
    #pragma unroll
    for (int nt = 0; nt < 4; ++nt)
        #pragma unroll
        for (int r = 0; r < 16; ++r) acc[nt][r] = 0.0f;

    // ---- K loop: NO barriers. 1 conflict-free ds_read_b128 (A frag) +
    // 4 coalesced L2 dwordx4 (B frags) + 4 independent MFMA chains per step.
    #pragma unroll 2
    for (int ks = 0; ks < 32; ++ks) {
        B128 a;
        a.u = *(const uint4*)(As + (size_t)(ks * 64 + (l ^ (ks & 7))) * 8);
        #pragma unroll
        for (int nt = 0; nt < 4; ++nt) {
            const int nt2 = nt * 4 + w;
            B128 b;
            b.u = *(const uint4*)(Sf + (size_t)((nt2 * 32 + ks) * 64 + l) * 8);
            acc[nt] = __builtin_amdgcn_mfma_f32_32x32x16_bf16(a.v, b.v, acc[nt], 0, 0, 0);
        }
    }

    // ---- epilogue: transpose acc through LDS (reuse q buffer), p-loads
    // hoisted above the barrier so HBM latency hides under the transpose.
    // C/D layout (verified m74/m101): col = lane&31, row = (r&3)+8*(r>>2)+4*(lane>>5)
    #pragma unroll
    for (int h = 0; h < 2; ++h) {
        float4 pv[8];
        #pragma unroll
        for (int it = 0; it < 8; ++it) {
            const int u   = it * 256 + t;
            const int row = u >> 6;              // 0..31
            const int c0  = (u & 63) * 4;        // 0..252
            const size_t goff = (size_t)(m0 + row) * (2 * DIM) + 256 * h + c0;
            pv[it] = *(const float4*)(pq + goff);
        }
        __syncthreads();   // h=0: K-loop LDS reads done; h=1: prev half reads done
        #pragma unroll
        for (int i = 0; i < 2; ++i) {
            const int nt = 2 * h + i;
            const int colb = 128 * i + 32 * w + lane31;   // 0..255 within half
            #pragma unroll
            for (int r = 0; r < 16; ++r) {
                const int row = 4 * half + (r & 3) + 8 * (r >> 2);
                Cs[row * 256 + colb] = acc[nt][r];
            }
        }
        __syncthreads();
        #pragma unroll
        for (int it = 0; it < 8; ++it) {
            const int u   = it * 256 + t;
            const int row = u >> 6;
            const int c0  = (u & 63) * 4;
            float4 v = *(const float4*)(Cs + row * 256 + c0);
            const size_t goff = (size_t)(m0 + row) * (2 * DIM) + 256 * h + c0;
            v.x += pv[it].x; v.y += pv[it].y; v.z += pv[it].z; v.w += pv[it].w;
            nt_store4(v, out + goff);
        }
    }
}

extern "C" void kernel_launch(void* const* d_in, const int* in_sizes, int n_in,
                              void* d_out, int out_size, void* d_ws, size_t ws_size,
                              hipStream_t stream) {
    const float* pq = (const float*)d_in[0];
    const float* A  = (const float*)d_in[1];
    float* out = (float*)d_out;
    unsigned short* Sf = (unsigned short*)d_ws;   // 512*512*2 = 512 KB scratch

    prep_s_kernel<<<(DIM * DIM / 8) / 256, 256, 0, stream>>>(A, Sf);
    fused_gemm_kernel<<<65536 / BM, 256, 0, stream>>>(pq, Sf, out);
}

// Round 4
// 554.449 us; speedup vs baseline: 1.0475x; 1.0475x over previous
//
#include <hip/hip_runtime.h>
#include <hip/hip_bf16.h>

#define DIM 512
#define BM 32

typedef __bf16 bf16x8 __attribute__((ext_vector_type(8)));
typedef float f32x16 __attribute__((ext_vector_type(16)));

union B128 { uint4 u; bf16x8 v; };
union PK  { ushort4 h[2]; uint4 u; };

__device__ __forceinline__ unsigned short f2bf(float f) {
    union { __hip_bfloat16 b; unsigned short u; } c;
    c.b = __float2bfloat16(f);
    return c.u;
}

// S_frag: B-fragment-linear layout of S = A + A^T (bf16).
// chunk c = (nt2*32 + ks)*64 + l   (16 B = 8 bf16 each):
//   content = S[e][d0 .. d0+7],  e = nt2*32 + (l&31),  d0 = ks*16 + (l>>5)*8
// => a wave's B-fragment load for (nt2, ks) is 64 consecutive 16B chunks
//    (one fully-coalesced global_load_dwordx4, L2-resident).
__global__ void prep_s_kernel(const float* __restrict__ A,
                              unsigned short* __restrict__ Sf) {
    const int c   = blockIdx.x * 256 + threadIdx.x;   // 0..32767
    const int l   = c & 63;
    const int ks  = (c >> 6) & 31;
    const int nt2 = c >> 11;
    const int e   = nt2 * 32 + (l & 31);
    const int d0  = ks * 16 + (l >> 5) * 8;
    float4 r0 = *(const float4*)(A + (size_t)e * DIM + d0);
    float4 r1 = *(const float4*)(A + (size_t)e * DIM + d0 + 4);
    float cl[8];
    #pragma unroll
    for (int j = 0; j < 8; ++j) cl[j] = A[(size_t)(d0 + j) * DIM + e];
    ushort4 o0, o1;
    o0.x = f2bf(r0.x + cl[0]); o0.y = f2bf(r0.y + cl[1]);
    o0.z = f2bf(r0.z + cl[2]); o0.w = f2bf(r0.w + cl[3]);
    o1.x = f2bf(r1.x + cl[4]); o1.y = f2bf(r1.y + cl[5]);
    o1.z = f2bf(r1.z + cl[6]); o1.w = f2bf(r1.w + cl[7]);
    *(ushort4*)(Sf + (size_t)c * 8)     = o0;
    *(ushort4*)(Sf + (size_t)c * 8 + 4) = o1;
}

// out[b][0:512]   = p[b] + q[b] . S^T   (S symmetric)
// out[b][512:1024]= q[b]                 (exact fp32 copy, fused into staging)
//
// BM=32, 256 threads (4 waves), 32 KB LDS, __launch_bounds__(256,5):
// 5 blocks/CU (160 KiB LDS exactly) -> 20 waves/CU of independent HBM
// streams. Staging: two rounds of {8x float4 load batch, sched_barrier,
// store+convert+LDS} so loads are 8-deep in flight before any store
// issues (vmcnt retires in order). Plain stores (NT caused 1.57x HBM
// write amplification in R3). K loop barrier-free, B frags straight
// from L2. Epilogue: p-loads hoisted over the LDS transpose.
__global__ __launch_bounds__(256, 5) void fused_gemm_kernel(
        const float* __restrict__ pq,
        const unsigned short* __restrict__ Sf,
        float* __restrict__ out) {
    __shared__ __align__(16) unsigned char smem[32768];
    unsigned short* As = (unsigned short*)smem;   // 32x512 bf16, frag-linear
    float*          Cs = (float*)smem;            // epilogue: 32x256 f32

    const int t = threadIdx.x;
    const int l = t & 63;
    const int w = t >> 6;          // wave 0..3 == N position
    const int lane31 = l & 31;
    const int half   = l >> 5;
    const int m0 = blockIdx.x * BM;

    // ---- stage q: 32x512 fp32. Each thread-iter: one 16B bf16 chunk.
    // chunk (ks, lpos): lpos = row + 32*hi, holds q[row][ks*16+hi*8 ..+7],
    // stored at chunk index ks*64 + (lpos ^ (ks&7)).
    #pragma unroll
    for (int rnd = 0; rnd < 2; ++rnd) {
        float4 qv[8];
        #pragma unroll
        for (int pp = 0; pp < 4; ++pp) {
            const int p    = rnd * 4 + pp;
            const int c    = p * 256 + t;        // 0..2047
            const int row  = c >> 6;             // 0..31
            const int col0 = (c & 63) * 8;       // 0,8,..,504
            const size_t goff = (size_t)(m0 + row) * (2 * DIM) + DIM + col0;
            qv[2 * pp]     = *(const float4*)(pq + goff);
            qv[2 * pp + 1] = *(const float4*)(pq + goff + 4);
        }
        __builtin_amdgcn_sched_barrier(0);   // keep the 8-load batch ahead of stores
        #pragma unroll
        for (int pp = 0; pp < 4; ++pp) {
            const int p    = rnd * 4 + pp;
            const int c    = p * 256 + t;
            const int row  = c >> 6;
            const int w6   = c & 63;
            const int ks   = w6 >> 1;
            const int hi   = w6 & 1;
            const int col0 = w6 * 8;
            const size_t goff = (size_t)(m0 + row) * (2 * DIM) + DIM + col0;
            *(float4*)(out + goff)     = qv[2 * pp];
            *(float4*)(out + goff + 4) = qv[2 * pp + 1];
            PK pk;
            pk.h[0].x = f2bf(qv[2 * pp].x);     pk.h[0].y = f2bf(qv[2 * pp].y);
            pk.h[0].z = f2bf(qv[2 * pp].z);     pk.h[0].w = f2bf(qv[2 * pp].w);
            pk.h[1].x = f2bf(qv[2 * pp + 1].x); pk.h[1].y = f2bf(qv[2 * pp + 1].y);
            pk.h[1].z = f2bf(qv[2 * pp + 1].z); pk.h[1].w = f2bf(qv[2 * pp + 1].w);
            const int f = (row + 32 * hi) ^ (ks & 7);
            *(uint4*)(As + (size_t)(ks * 64 + f) * 8) = pk.u;
        }
    }
    __syncthreads();

    f32x16 acc[4];
    #pragma unroll
    for (int nt = 0; nt < 4; ++nt)
        #pragma unroll
        for (int r = 0; r < 16; ++r) acc[nt][r] = 0.0f;

    // ---- K loop: NO barriers. 1 conflict-free ds_read_b128 (A frag) +
    // 4 coalesced L2 dwordx4 (B frags) + 4 independent MFMA chains per step.
    #pragma unroll 2
    for (int ks = 0; ks < 32; ++ks) {
        B128 a;
        a.u = *(const uint4*)(As + (size_t)(ks * 64 + (l ^ (ks & 7))) * 8);
        #pragma unroll
        for (int nt = 0; nt < 4; ++nt) {
            const int nt2 = nt * 4 + w;
            B128 b;
            b.u = *(const uint4*)(Sf + (size_t)((nt2 * 32 + ks) * 64 + l) * 8);
            acc[nt] = __builtin_amdgcn_mfma_f32_32x32x16_bf16(a.v, b.v, acc[nt], 0, 0, 0);
        }
    }

    // ---- epilogue: transpose acc through LDS (reuse q buffer), p-loads
    // hoisted above the barrier so HBM latency hides under the transpose.
    // C/D layout (verified m74/m101): col = lane&31, row = (r&3)+8*(r>>2)+4*(lane>>5)
    #pragma unroll
    for (int h = 0; h < 2; ++h) {
        float4 pv[8];
        #pragma unroll
        for (int it = 0; it < 8; ++it) {
            const int u   = it * 256 + t;
            const int row = u >> 6;              // 0..31
            const int c0  = (u & 63) * 4;        // 0..252
            const size_t goff = (size_t)(m0 + row) * (2 * DIM) + 256 * h + c0;
            pv[it] = *(const float4*)(pq + goff);
        }
        __syncthreads();   // h=0: K-loop LDS reads done; h=1: prev half reads done
        #pragma unroll
        for (int i = 0; i < 2; ++i) {
            const int nt = 2 * h + i;
            const int colb = 128 * i + 32 * w + lane31;   // 0..255 within half
            #pragma unroll
            for (int r = 0; r < 16; ++r) {
                const int row = 4 * half + (r & 3) + 8 * (r >> 2);
                Cs[row * 256 + colb] = acc[nt][r];
            }
        }
        __syncthreads();
        #pragma unroll
        for (int it = 0; it < 8; ++it) {
            const int u   = it * 256 + t;
            const int row = u >> 6;
            const int c0  = (u & 63) * 4;
            float4 v = *(const float4*)(Cs + row * 256 + c0);
            const size_t goff = (size_t)(m0 + row) * (2 * DIM) + 256 * h + c0;
            v.x += pv[it].x; v.y += pv[it].y; v.z += pv[it].z; v.w += pv[it].w;
            *(float4*)(out + goff) = v;
        }
    }
}

extern "C" void kernel_launch(void* const* d_in, const int* in_sizes, int n_in,
                              void* d_out, int out_size, void* d_ws, size_t ws_size,
                              hipStream_t stream) {
    const float* pq = (const float*)d_in[0];
    const float* A  = (const float*)d_in[1];
    float* out = (float*)d_out;
    unsigned short* Sf = (unsigned short*)d_ws;   // 512*512*2 = 512 KB scratch

    prep_s_kernel<<<(DIM * DIM / 8) / 256, 256, 0, stream>>>(A, Sf);
    fused_gemm_kernel<<<65536 / BM, 256, 0, stream>>>(pq, Sf, out);
}

// Round 5
// 485.742 us; speedup vs baseline: 1.1957x; 1.1414x over previous
//
#include <hip/hip_runtime.h>
#include <hip/hip_bf16.h>

#define DIM 512
#define BM 64

typedef __bf16 bf16x8 __attribute__((ext_vector_type(8)));
typedef float f32x16 __attribute__((ext_vector_type(16)));

union B128 { uint4 u; bf16x8 v; };

__device__ __forceinline__ unsigned short f2bf(float f) {
    union { __hip_bfloat16 b; unsigned short u; } c;
    c.b = __float2bfloat16(f);
    return c.u;
}

// S_frag: B-fragment-linear layout of S = A + A^T (bf16).
// chunk c = (nt2*32 + ks)*64 + l   (16 B = 8 bf16 each):
//   content = S[e][d0 .. d0+7],  e = nt2*32 + (l&31),  d0 = ks*16 + (l>>5)*8
// => a wave's B-fragment load for (nt2, ks) is 64 consecutive 16B chunks
//    (one fully-coalesced global_load_dwordx4, L2-resident).
__global__ void prep_s_kernel(const float* __restrict__ A,
                              unsigned short* __restrict__ Sf) {
    const int c   = blockIdx.x * 256 + threadIdx.x;   // 0..32767
    const int l   = c & 63;
    const int ks  = (c >> 6) & 31;
    const int nt2 = c >> 11;
    const int e   = nt2 * 32 + (l & 31);
    const int d0  = ks * 16 + (l >> 5) * 8;
    float4 r0 = *(const float4*)(A + (size_t)e * DIM + d0);
    float4 r1 = *(const float4*)(A + (size_t)e * DIM + d0 + 4);
    float cl[8];
    #pragma unroll
    for (int j = 0; j < 8; ++j) cl[j] = A[(size_t)(d0 + j) * DIM + e];
    ushort4 o0, o1;
    o0.x = f2bf(r0.x + cl[0]); o0.y = f2bf(r0.y + cl[1]);
    o0.z = f2bf(r0.z + cl[2]); o0.w = f2bf(r0.w + cl[3]);
    o1.x = f2bf(r1.x + cl[4]); o1.y = f2bf(r1.y + cl[5]);
    o1.z = f2bf(r1.z + cl[6]); o1.w = f2bf(r1.w + cl[7]);
    *(ushort4*)(Sf + (size_t)c * 8)     = o0;
    *(ushort4*)(Sf + (size_t)c * 8 + 4) = o1;
}

// out[b][0:512]   = p[b] + q[b] . S^T   (S symmetric)
// out[b][512:1024]= q[b]                 (exact fp32 copy, fused into staging)
//
// R1 structure (BM=64, 512 thr, 64 KB LDS, 2 blk/CU) + ILP surgery:
//  - staging: 16-deep global-load batch (sched_barrier fence) before any
//    store/convert -> no serialized load->store round trips.
//    Store pattern: single-instruction full-128B-line coverage (R3/R4's
//    split-line pattern caused 1.54x HBM write amplification).
//  - K loop: barrier-free; A frags from swizzled LDS (conflict-free),
//    B frags straight from L2 (Sf frag-linear, fully coalesced).
//  - epilogue: wave-local LDS transpose (private 8 KB slice, XOR-swizzled,
//    write 2-way / read-b128 optimal) -> NO barriers in the epilogue;
//    p-loads hoisted with the store-matching mapping so HBM latency hides
//    under the transpose. Only ONE __syncthreads after the K loop.
__global__ __launch_bounds__(512, 2) void fused_gemm_kernel(
        const float* __restrict__ pq,
        const unsigned short* __restrict__ Sf,
        float* __restrict__ out) {
    __shared__ __align__(16) unsigned char smem[65536];
    unsigned short* As = (unsigned short*)smem;   // 64x512 bf16, frag-linear
    float*          Cs = (float*)smem;            // epilogue: 8 KB per wave

    const int t = threadIdx.x;
    const int l = t & 63;
    const int w = t >> 6;          // wave 0..7
    const int wm = w >> 2;         // 0..1  (M position, 32 rows)
    const int wn = w & 3;          // 0..3  (N position within 128-chunk)
    const int lane31 = l & 31;
    const int half   = l >> 5;
    const int m0 = blockIdx.x * BM;

    // ---- stage q: 64x512 fp32 -> bf16 frag-linear LDS; exact q copy to out.
    // 16-deep load batch first (fence), then store+convert+LDS phase.
    float4 qv[16];
    #pragma unroll
    for (int p = 0; p < 16; ++p) {
        const int u   = p * 512 + t;
        const int row = u >> 7;              // 0..63
        const int col = (u & 127) * 4;       // 0..508
        qv[p] = *(const float4*)(pq + (size_t)(m0 + row) * (2 * DIM) + DIM + col);
    }
    __builtin_amdgcn_sched_barrier(0);   // all 16 loads issue before any store
    #pragma unroll
    for (int p = 0; p < 16; ++p) {
        const int u   = p * 512 + t;
        const int row = u >> 7;
        const int col = (u & 127) * 4;
        const size_t goff = (size_t)(m0 + row) * (2 * DIM) + DIM + col;
        *(float4*)(out + goff) = qv[p];      // fused exact q copy (full-line)
        ushort4 qb;
        qb.x = f2bf(qv[p].x); qb.y = f2bf(qv[p].y);
        qb.z = f2bf(qv[p].z); qb.w = f2bf(qv[p].w);
        const int mt   = row >> 5;
        const int ks   = col >> 4;
        const int lpos = (row & 31) + ((col >> 3) & 1) * 32;
        const int chunk = (mt * 32 + ks) * 64 + (lpos ^ (ks & 7));
        *(ushort4*)(As + (size_t)chunk * 8 + (col & 7)) = qb;   // 8 B, aligned
    }
    __syncthreads();

    f32x16 acc[4];
    #pragma unroll
    for (int nt = 0; nt < 4; ++nt)
        #pragma unroll
        for (int r = 0; r < 16; ++r) acc[nt][r] = 0.0f;

    // ---- K loop: NO barriers. 1 conflict-free ds_read_b128 (A frag) +
    // 4 coalesced L2 dwordx4 (B frags) + 4 independent MFMA chains per step.
    #pragma unroll 2
    for (int ks = 0; ks < 32; ++ks) {
        B128 a;
        const int achunk = (wm * 32 + ks) * 64 + (l ^ (ks & 7));
        a.u = *(const uint4*)(As + (size_t)achunk * 8);
        #pragma unroll
        for (int nt = 0; nt < 4; ++nt) {
            const int nt2 = nt * 4 + wn;
            B128 b;
            b.u = *(const uint4*)(Sf + (size_t)((nt2 * 32 + ks) * 64 + l) * 8);
            acc[nt] = __builtin_amdgcn_mfma_f32_32x32x16_bf16(a.v, b.v, acc[nt], 0, 0, 0);
        }
    }

    // ---- epilogue: wave-local swizzled LDS transpose, barrier-free.
    // C/D layout (verified m74/m101): col = lane&31, row = (r&3)+8*(r>>2)+4*(lane>>5)
    // Wave region: 32 rows x 64 f32 (local col c = 32*i + lane31, i = nt within
    // pass). Swizzle: f4-group g stored at g ^ (lrow & 7).
    const int wbase = w * 2048;   // f32 units; 8 KB per wave
    #pragma unroll
    for (int h = 0; h < 2; ++h) {
        // p-loads, store-matching mapping (8 full 128B lines per instruction)
        float4 pv[8];
        #pragma unroll
        for (int it = 0; it < 8; ++it) {
            const int lrow = it * 4 + (l >> 4);
            const int f4   = l & 15;
            const int grow = m0 + 32 * wm + lrow;
            const int gcol = 128 * (2 * h + (f4 >> 3)) + 32 * wn + (f4 & 7) * 4;
            pv[it] = *(const float4*)(pq + (size_t)grow * (2 * DIM) + gcol);
        }
        if (h == 0) __syncthreads();   // other waves' K-loop As reads done
        #pragma unroll
        for (int i = 0; i < 2; ++i) {
            const int nt = 2 * h + i;
            #pragma unroll
            for (int r = 0; r < 16; ++r) {
                const int lrow = 4 * half + (r & 3) + 8 * (r >> 2);
                const int c    = 32 * i + lane31;
                const int g    = (c >> 2) ^ (lrow & 7);
                Cs[wbase + lrow * 64 + g * 4 + (c & 3)] = acc[nt][r];
            }
        }
        #pragma unroll
        for (int it = 0; it < 8; ++it) {
            const int lrow = it * 4 + (l >> 4);
            const int f4   = l & 15;
            const int gr   = f4 ^ (lrow & 7);
            float4 v = *(const float4*)(Cs + wbase + lrow * 64 + gr * 4);
            const int grow = m0 + 32 * wm + lrow;
            const int gcol = 128 * (2 * h + (f4 >> 3)) + 32 * wn + (f4 & 7) * 4;
            v.x += pv[it].x; v.y += pv[it].y; v.z += pv[it].z; v.w += pv[it].w;
            *(float4*)(out + (size_t)grow * (2 * DIM) + gcol) = v;
        }
    }
}

extern "C" void kernel_launch(void* const* d_in, const int* in_sizes, int n_in,
                              void* d_out, int out_size, void* d_ws, size_t ws_size,
                              hipStream_t stream) {
    const float* pq = (const float*)d_in[0];
    const float* A  = (const float*)d_in[1];
    float* out = (float*)d_out;
    unsigned short* Sf = (unsigned short*)d_ws;   // 512*512*2 = 512 KB scratch

    prep_s_kernel<<<(DIM * DIM / 8) / 256, 256, 0, stream>>>(A, Sf);
    fused_gemm_kernel<<<65536 / BM, 512, 0, stream>>>(pq, Sf, out);
}